// Round 16
// baseline (392.542 us; speedup 1.0000x reference)
//
#include <hip/hip_runtime.h>

typedef __attribute__((ext_vector_type(8))) short short8;
typedef __attribute__((ext_vector_type(4))) float f32x4;

#define SDIM 48
#define SS   (48*48)
#define SSS  (48*48*48)
#define CIN  120
#define CIP  128
#define NCO  24
#define ZP   52
#define NTAP 125

#define WP_USHORTS (4*25*5*32*32)              // 512000
#define WP_BYTES   ((size_t)WP_USHORTS*2)
#define XT_USHORTS ((size_t)2*48*48*ZP*CIP)
#define XT_BYTES   (XT_USHORTS*2)
#define WTOT_F32   (NCO*CIN*NTAP)

// A-tile in LDS (per buffer): 1664 chunks of 16B, linear in gload_lds order.
// chunk(row, zp, slot_phys): content = global ci-slot  slot_phys ^ ((zp>>1)&3).
// Read (row, zp, slot=l4) -> byte row*3328 + zp*64 + ((l4^((zp>>1)&3))<<4).
// 2-way bank aliasing = free (verified r9/r11: ~2.2e5 conflicts).
#define A_CHUNKS 1664
#define ABUF_USH 13312              // 26,624 B per buffer; dbuf = 53,248 B
#define GLP      25                 // gl pitch: odd -> bijective mod 32 banks

__device__ __forceinline__ unsigned short f2bf(float f){
    unsigned u = __float_as_uint(f);
    u = (u + 0x7FFFu + ((u >> 16) & 1u)) >> 16;
    return (unsigned short)u;
}

__device__ __forceinline__ void gload_lds16(const unsigned short* g, unsigned short* l)
{
    __builtin_amdgcn_global_load_lds(
        (const __attribute__((address_space(1))) unsigned int*)g,
        (__attribute__((address_space(3))) unsigned int*)l,
        16, 0, 0);
}

// ---------------- MFMA path ----------------

// x[b][ci][X][Y][Z] f32 -> xt[b][ix][iy][zp][ci] bf16 (zp=z+2 halo, ci pad 128)
__global__ __launch_bounds__(256)
void transpose_x(const float* __restrict__ x, unsigned short* __restrict__ xt)
{
    __shared__ unsigned short sm[CIN*50];
    int bid = blockIdx.x;
    const int iy = bid % 48; bid /= 48;
    const int ix = bid % 48;
    const int b  = bid / 48;
    const int tid = threadIdx.x;

    const float* __restrict__ src = x + (size_t)b*CIN*SSS + ((size_t)ix*48 + iy)*48;
    for (int idx = tid; idx < CIN*48; idx += 256) {
        int ci = idx / 48, z = idx - ci*48;
        sm[ci*50 + z] = f2bf(src[(size_t)ci*SSS + z]);
    }
    __syncthreads();
    unsigned short* __restrict__ dst = xt + (((size_t)(b*48 + ix)*48) + iy)*ZP*CIP;
    for (int odx = tid; odx < ZP*CIP; odx += 256) {
        int zp = odx >> 7, ci = odx & 127;
        int z = zp - 2;
        unsigned short v = 0;
        if (ci < CIN && (unsigned)z < 48u) v = sm[ci*50 + z];
        dst[odx] = v;
    }
}

// w[co][ci][dx][dy][dz] f32 -> wp[cc][t][dz][co 32][cik 32] bf16 (zero-padded)
__global__ __launch_bounds__(256)
void repack_w_bf16(const float* __restrict__ w, unsigned short* __restrict__ wp)
{
    int idx = blockIdx.x*256 + threadIdx.x;
    if (idx >= WP_USHORTS) return;
    int cik = idx & 31;
    int co  = (idx >> 5) & 31;
    int dz  = (idx >> 10) % 5;
    int t   = (idx / 5120) % 25;
    int cc  = idx / 128000;
    int ci  = cc*32 + cik;
    float v = 0.f;
    if (co < NCO && ci < CIN)
        v = w[(size_t)(co*CIN + ci)*NTAP + t*5 + dz];
    wp[idx] = f2bf(v);
}

#define MFMA16(a,b,c) __builtin_amdgcn_mfma_f32_16x16x32_bf16(a,b,c,0,0,0)

__global__ __launch_bounds__(128, 3)
void conv_mfma(const unsigned short* __restrict__ xt,
               const unsigned short* __restrict__ wp,
               const float* __restrict__ x,
               float* __restrict__ out)
{
    __shared__ __align__(16) unsigned short As[2*ABUF_USH];  // 53,248 B dbuf

    // bijective XCD swizzle: 1152 blocks = 8 XCDs x 144 contiguous logical ids
    int bid = (blockIdx.x & 7) * 144 + (blockIdx.x >> 3);
    const int oyq = bid % 12; bid /= 12;
    const int ox = bid % 48;
    const int b  = bid / 48;

    const int tid = threadIdx.x;            // 0..127, 2 waves
    const int wave = tid >> 6, lane = tid & 63;
    const int l15 = lane & 15, l4 = lane >> 4;
    const int iy0 = oyq*4 - 2;

    // valid dx range (block-uniform, contiguous): ix = ox+dx-2 in [0,48)
    const int dxlo = (ox < 2) ? (2 - ox) : 0;
    const int dxhi = (ox > 45) ? (49 - ox) : 4;
    const int ndx  = dxhi - dxlo + 1;

    // staging descriptors: 1664 chunks = 13 insts x 128 threads
    int goff[13];
    bool ok[13];
#pragma unroll
    for (int k = 0; k < 13; ++k) {
        int L = k*128 + tid;
        int row = L / 208, rem = L - row*208;
        int zp = rem >> 2, sf = rem & 3;
        int sg = sf ^ ((zp >> 1) & 3);
        int iy = iy0 + row;
        ok[k]   = (unsigned)iy < 48u;
        goff[k] = (iy*52 + zp)*128 + sg*8;
    }
    // zero source: xt's leading 512B (zp=0,1 halo of b=0,ix=0,iy=0) is all zeros
    const unsigned short* zsrc = xt + (lane & 31)*8;

    // wave owns 2 oy lines (M=96): acc[oh][z-block][n-tile]
    f32x4 acc[2][3][2];
#pragma unroll
    for (int oh = 0; oh < 2; ++oh)
#pragma unroll
      for (int zb = 0; zb < 3; ++zb)
#pragma unroll
        for (int nt = 0; nt < 2; ++nt) acc[oh][zb][nt] = (f32x4){0,0,0,0};

    // prologue: stage first tile into buf0, drain, publish
    {
        const unsigned short* __restrict__ slab =
            xt + (size_t)(b*48 + ox + dxlo - 2)*(48*52*128);
#pragma unroll
        for (int k = 0; k < 13; ++k) {
            const unsigned short* src = ok[k] ? (slab + goff[k]) : zsrc;
            gload_lds16(src, As + k*1024 + wave*512);
        }
    }
    asm volatile("s_waitcnt vmcnt(0)" ::: "memory");
    __builtin_amdgcn_sched_barrier(0);
    __syncthreads();

    int pcur = 0;
#pragma unroll 1
    for (int cc = 0; cc < 4; ++cc) {
#pragma unroll 1
      for (int dxi = 0; dxi < ndx; ++dxi) {
        const int dx = dxlo + dxi;
        unsigned short* __restrict__ curb = As + pcur*ABUF_USH;
        unsigned short* __restrict__ nxtb = As + (pcur^1)*ABUF_USH;

        // next step's source slab (stage groups issued inside the phases)
        const int more = (dxi + 1 < ndx);
        const int cc2 = more ? cc : cc + 1;
        const int dx2 = more ? dx + 1 : dxlo;
        const bool do_stage = (cc2 < 4);
        const unsigned short* __restrict__ slab2 =
            xt + (size_t)(b*48 + ox + dx2 - 2)*(48*52*128) + cc2*32;

        const unsigned short* __restrict__ wdxb =
            wp + (size_t)cc*128000 + (size_t)dx*25600 + l15*32 + l4*8;
        const char* __restrict__ asb = (const char*)curb;

        // 5 phases (one per dz): stage-group || B-loads || 3x(6 ds_read + 24 MFMA)
#pragma unroll
        for (int dz = 0; dz < 5; ++dz) {
            // stage group: phases 0-2 issue 3 gloads, phases 3-4 issue 2
            if (do_stage) {
                const int g0 = (dz < 3) ? dz*3 : 9 + (dz - 3)*2;
                const int gn = (dz < 3) ? 3 : 2;
#pragma unroll
                for (int j = 0; j < gn; ++j) {
                    const int k = g0 + j;
                    const unsigned short* src = ok[k] ? (slab2 + goff[k]) : zsrc;
                    gload_lds16(src, nxtb + k*1024 + wave*512);
                }
            }
            short8 bb[5][2];                 // B reg-cache for this dz
#pragma unroll
            for (int dy = 0; dy < 5; ++dy) {
                bb[dy][0] = *(const short8*)(wdxb + dy*5120 + dz*1024);
                bb[dy][1] = *(const short8*)(wdxb + dy*5120 + dz*1024 + 512);
            }
            __builtin_amdgcn_s_setprio(1);
#pragma unroll
            for (int rp = 0; rp < 3; ++rp) { // row pairs: reads first, then MFMAs
                short8 a[2][3];
#pragma unroll
                for (int ri = 0; ri < 2; ++ri) {
                    const int r = rp*2 + ri;
                    const char* __restrict__ ab = asb + (wave*2 + r)*3328;
#pragma unroll
                    for (int zb = 0; zb < 3; ++zb) {
                        const int zp = l15 + dz + zb*16;
                        const int off = zp*64 + ((l4 ^ ((zp >> 1) & 3)) << 4);
                        a[ri][zb] = *(const short8*)(ab + off);
                    }
                }
#pragma unroll
                for (int ri = 0; ri < 2; ++ri) {
                    const int r = rp*2 + ri;
                    if (r <= 4) {            // oh=0, dy=r
#pragma unroll
                        for (int zb = 0; zb < 3; ++zb) {
                            acc[0][zb][0] = MFMA16(a[ri][zb], bb[r][0], acc[0][zb][0]);
                            acc[0][zb][1] = MFMA16(a[ri][zb], bb[r][1], acc[0][zb][1]);
                        }
                    }
                    if (r >= 1) {            // oh=1, dy=r-1
#pragma unroll
                        for (int zb = 0; zb < 3; ++zb) {
                            acc[1][zb][0] = MFMA16(a[ri][zb], bb[r-1][0], acc[1][zb][0]);
                            acc[1][zb][1] = MFMA16(a[ri][zb], bb[r-1][1], acc[1][zb][1]);
                        }
                    }
                }
            }
            __builtin_amdgcn_s_setprio(0);
        }

        // step end: stage DMA (issued over the 5 phases) must land; swap buffers
        asm volatile("s_waitcnt vmcnt(0)" ::: "memory");
        __builtin_amdgcn_sched_barrier(0);
        __syncthreads();
        pcur ^= 1;
      }
    }

    float* gl = (float*)As;                   // 192*GLP f32 = 19,200 B < 53,248

    // C/D: col = lane&15 (co in tile), row = (lane>>4)*4 + r (z in 16-tile)
#pragma unroll
    for (int nt = 0; nt < 2; ++nt) {
        const int co = nt*16 + l15;
        if (co < NCO) {
#pragma unroll
            for (int oh = 0; oh < 2; ++oh)
#pragma unroll
              for (int zb = 0; zb < 3; ++zb)
#pragma unroll
                for (int r = 0; r < 4; ++r) {
                    const int z0 = zb*16 + l4*4 + r;
                    gl[((wave*2 + oh)*48 + z0)*GLP + co] =
                        1.f / (1.f + __expf(-acc[oh][zb][nt][r]));
                }
        }
    }
    __syncthreads();

    // epilogue: 384 items = (point 192) x (channel-half 2), fp32 x re-read
    for (int i = tid; i < 384; i += 128) {
        const int pnt = i % 192;
        const int half = i / 192;
        const int z = pnt % 48, oyl = pnt / 48;
        const int oy2 = oyq*4 + oyl;
        const size_t sp = ((size_t)ox*48 + oy2)*48 + z;
        const float* __restrict__ xsp = x   + (size_t)b*CIN*SSS + sp;
        float*       __restrict__ osp = out + (size_t)b*CIN*SSS + sp;
        const float* __restrict__ gp = gl + pnt*GLP;
        for (int c = half*60; c < half*60 + 60; ++c) {
            float v = xsp[(size_t)c*SSS];
            float o;
            if (c < 32)       o = v > 0.f ? v : 0.f;
            else if (c < 80)  o = v * gp[(c - 32) / 3];
            else              o = v * gp[16 + (c - 80) / 5];
            osp[(size_t)c*SSS] = o;
        }
    }
}

// ---------------- fallback paths (verified rounds 1-2) ----------------

__global__ __launch_bounds__(256)
void repack_w_f32(const float* __restrict__ w, float* __restrict__ wpf)
{
    int idx = blockIdx.x * 256 + threadIdx.x;
    if (idx >= WTOT_F32) return;
    int co = idx % NCO;
    int t  = idx / NCO;
    wpf[idx] = w[co * (CIN * NTAP) + t];
}

__global__ __launch_bounds__(128)
void gated_act_f32(const float* __restrict__ x,
                   const float* __restrict__ wpf,
                   float* __restrict__ out)
{
    const int gid = blockIdx.x * 128 + threadIdx.x;
    const int oz = gid % SDIM;
    int r = gid / SDIM;
    const int oy = r % SDIM; r /= SDIM;
    const int ox = r % SDIM;
    const int b  = r / SDIM;

    const float* __restrict__ xb = x + (size_t)b * CIN * SSS;
    float acc[NCO];
#pragma unroll
    for (int i = 0; i < NCO; ++i) acc[i] = 0.f;

    int izc[5]; bool okz[5];
#pragma unroll
    for (int dz = 0; dz < 5; ++dz) {
        int iz = oz + dz - 2;
        okz[dz] = (unsigned)iz < (unsigned)SDIM;
        izc[dz] = okz[dz] ? iz : 0;
    }
    for (int ci = 0; ci < CIN; ++ci) {
        const float* __restrict__ xc = xb + (size_t)ci * SSS;
        const float* __restrict__ wc = wpf + ci * (NTAP * NCO);
#pragma unroll 1
        for (int dx = 0; dx < 5; ++dx) {
            const int ix = ox + dx - 2;
            const bool okx = (unsigned)ix < (unsigned)SDIM;
            const int ixc = okx ? ix : 0;
#pragma unroll 1
            for (int dy = 0; dy < 5; ++dy) {
                const int iy = oy + dy - 2;
                const bool oky = (unsigned)iy < (unsigned)SDIM;
                const int iyc = oky ? iy : 0;
                const bool okxy = okx && oky;
                const float* __restrict__ xrow = xc + ixc * SS + iyc * SDIM;
                float xv[5];
#pragma unroll
                for (int dz = 0; dz < 5; ++dz) {
                    float v = xrow[izc[dz]];
                    xv[dz] = (okxy && okz[dz]) ? v : 0.f;
                }
                const float* __restrict__ wr = wc + (dx * 25 + dy * 5) * NCO;
#pragma unroll
                for (int dz = 0; dz < 5; ++dz) {
                    const float v = xv[dz];
#pragma unroll
                    for (int co = 0; co < NCO; ++co)
                        acc[co] = fmaf(v, wr[dz * NCO + co], acc[co]);
                }
            }
        }
    }
    float g[NCO];
#pragma unroll
    for (int co = 0; co < NCO; ++co)
        g[co] = 1.f / (1.f + __expf(-acc[co]));

    const size_t sbase = (size_t)b * CIN * SSS + ox * SS + oy * SDIM + oz;
    float* __restrict__ ob = out + sbase;
    const float* __restrict__ xs = x + sbase;
#pragma unroll
    for (int c = 0; c < 32; ++c) {
        float v = xs[(size_t)c * SSS];
        ob[(size_t)c * SSS] = v > 0.f ? v : 0.f;
    }
#pragma unroll
    for (int m = 0; m < 16; ++m) {
        const float gv = g[m];
#pragma unroll
        for (int k = 0; k < 3; ++k) {
            const int c = 32 + m * 3 + k;
            ob[(size_t)c * SSS] = xs[(size_t)c * SSS] * gv;
        }
    }
#pragma unroll
    for (int m = 0; m < 8; ++m) {
        const float gv = g[16 + m];
#pragma unroll
        for (int k = 0; k < 5; ++k) {
            const int c = 80 + m * 5 + k;
            ob[(size_t)c * SSS] = xs[(size_t)c * SSS] * gv;
        }
    }
}

extern "C" void kernel_launch(void* const* d_in, const int* in_sizes, int n_in,
                              void* d_out, int out_size, void* d_ws, size_t ws_size,
                              hipStream_t stream)
{
    const float* x = (const float*)d_in[0];
    const float* w = (const float*)d_in[1];
    float* out = (float*)d_out;

    if (ws_size >= WP_BYTES + XT_BYTES) {
        unsigned short* wp  = (unsigned short*)d_ws;
        unsigned short* xtb = (unsigned short*)((char*)d_ws + WP_BYTES);
        hipLaunchKernelGGL(repack_w_bf16, dim3((WP_USHORTS + 255) / 256), dim3(256),
                           0, stream, w, wp);
        hipLaunchKernelGGL(transpose_x, dim3(2*48*48), dim3(256), 0, stream, x, xtb);
        hipLaunchKernelGGL(conv_mfma, dim3(2*48*12), dim3(128), 0, stream,
                           xtb, wp, x, out);
    } else if (ws_size >= (size_t)WTOT_F32 * 4) {
        float* wpf = (float*)d_ws;
        hipLaunchKernelGGL(repack_w_f32, dim3((WTOT_F32 + 255) / 256), dim3(256),
                           0, stream, w, wpf);
        hipLaunchKernelGGL(gated_act_f32, dim3(2*SSS/128), dim3(128), 0, stream,
                           x, wpf, out);
    }
}

// Round 17
// 363.582 us; speedup vs baseline: 1.0797x; 1.0797x over previous
//
#include <hip/hip_runtime.h>

typedef __attribute__((ext_vector_type(8))) short short8;
typedef __attribute__((ext_vector_type(8))) unsigned short ushort8;
typedef __attribute__((ext_vector_type(4))) float f32x4;

#define SDIM 48
#define SS   (48*48)
#define SSS  (48*48*48)
#define CIN  120
#define CIP  128
#define NCO  24
#define ZP   52
#define NTAP 125

#define WP_USHORTS (4*25*5*32*32)              // 512000
#define WP_BYTES   ((size_t)WP_USHORTS*2)
#define XT_USHORTS ((size_t)2*48*48*ZP*CIP)
#define XT_BYTES   (XT_USHORTS*2)
#define WTOT_F32   (NCO*CIN*NTAP)

// A-tile in LDS: 1664 chunks of 16B at byte L*16 (L = k*128 + tid).
// chunk(row, zp, slot_phys): content = global ci-slot  slot_phys ^ ((zp>>1)&3).
// Read (row, zp, slot=l4) -> byte row*3328 + zp*64 + ((l4^((zp>>1)&3))<<4).
// 2-way bank aliasing = free (verified r9/r11: ~2.2e5 conflicts).
#define A_CHUNKS 1664
#define ABUF_USH 13312              // 26,624 B single buffer
#define GLP      25                 // gl pitch: odd -> bijective mod 32 banks

__device__ __forceinline__ unsigned short f2bf(float f){
    unsigned u = __float_as_uint(f);
    u = (u + 0x7FFFu + ((u >> 16) & 1u)) >> 16;
    return (unsigned short)u;
}

// ---------------- MFMA path ----------------

// x[b][ci][X][Y][Z] f32 -> xt[b][ix][iy][zp][ci] bf16 (zp=z+2 halo, ci pad 128)
__global__ __launch_bounds__(256)
void transpose_x(const float* __restrict__ x, unsigned short* __restrict__ xt)
{
    __shared__ unsigned short sm[CIN*50];
    int bid = blockIdx.x;
    const int iy = bid % 48; bid /= 48;
    const int ix = bid % 48;
    const int b  = bid / 48;
    const int tid = threadIdx.x;

    const float* __restrict__ src = x + (size_t)b*CIN*SSS + ((size_t)ix*48 + iy)*48;
    for (int idx = tid; idx < CIN*48; idx += 256) {
        int ci = idx / 48, z = idx - ci*48;
        sm[ci*50 + z] = f2bf(src[(size_t)ci*SSS + z]);
    }
    __syncthreads();
    unsigned short* __restrict__ dst = xt + (((size_t)(b*48 + ix)*48) + iy)*ZP*CIP;
    for (int odx = tid; odx < ZP*CIP; odx += 256) {
        int zp = odx >> 7, ci = odx & 127;
        int z = zp - 2;
        unsigned short v = 0;
        if (ci < CIN && (unsigned)z < 48u) v = sm[ci*50 + z];
        dst[odx] = v;
    }
}

// w[co][ci][dx][dy][dz] f32 -> wp[cc][t][dz][co 32][cik 32] bf16 (zero-padded)
__global__ __launch_bounds__(256)
void repack_w_bf16(const float* __restrict__ w, unsigned short* __restrict__ wp)
{
    int idx = blockIdx.x*256 + threadIdx.x;
    if (idx >= WP_USHORTS) return;
    int cik = idx & 31;
    int co  = (idx >> 5) & 31;
    int dz  = (idx >> 10) % 5;
    int t   = (idx / 5120) % 25;
    int cc  = idx / 128000;
    int ci  = cc*32 + cik;
    float v = 0.f;
    if (co < NCO && ci < CIN)
        v = w[(size_t)(co*CIN + ci)*NTAP + t*5 + dz];
    wp[idx] = f2bf(v);
}

#define MFMA16(a,b,c) __builtin_amdgcn_mfma_f32_16x16x32_bf16(a,b,c,0,0,0)

__global__ __launch_bounds__(128, 2)
void conv_mfma(const unsigned short* __restrict__ xt,
               const unsigned short* __restrict__ wp,
               const float* __restrict__ x,
               float* __restrict__ out)
{
    __shared__ __align__(16) unsigned short As[ABUF_USH];   // 26,624 B

    // bijective XCD swizzle: 1152 blocks = 8 XCDs x 144 contiguous logical ids
    int bid = (blockIdx.x & 7) * 144 + (blockIdx.x >> 3);
    const int oyq = bid % 12; bid /= 12;
    const int ox = bid % 48;
    const int b  = bid / 48;

    const int tid = threadIdx.x;            // 0..127, 2 waves
    const int lane = tid & 63;
    const int wave = tid >> 6;
    const int l15 = lane & 15, l4 = lane >> 4;
    const int iy0 = oyq*4 - 2;

    // valid dx range (block-uniform, contiguous): ix = ox+dx-2 in [0,48)
    const int dxlo = (ox < 2) ? (2 - ox) : 0;
    const int dxhi = (ox > 45) ? (49 - ox) : 4;
    const int ndx  = dxhi - dxlo + 1;

    // staging descriptors: 1664 chunks = 13 insts x 128 threads; thread tid
    // handles chunk L = k*128 + tid -> LDS byte L*16 (= ushort k*1024 + tid*8)
    int goff[13];
    bool ok[13];
#pragma unroll
    for (int k = 0; k < 13; ++k) {
        int L = k*128 + tid;
        int row = L / 208, rem = L - row*208;
        int zp = rem >> 2, sf = rem & 3;
        int sg = sf ^ ((zp >> 1) & 3);
        int iy = iy0 + row;
        ok[k]   = (unsigned)iy < 48u;
        goff[k] = (iy*52 + zp)*128 + sg*8;
    }
    const ushort8 zv = {0,0,0,0,0,0,0,0};

    // wave owns 2 oy lines (M=96): acc[oh][z-block][n-tile]
    f32x4 acc[2][3][2];
#pragma unroll
    for (int oh = 0; oh < 2; ++oh)
#pragma unroll
      for (int zb = 0; zb < 3; ++zb)
#pragma unroll
        for (int nt = 0; nt < 2; ++nt) acc[oh][zb][nt] = (f32x4){0,0,0,0};

    ushort8 stg[13];

    // prologue: load + write first tile (cc=0, dx=dxlo)
    {
        const unsigned short* __restrict__ slab =
            xt + (size_t)(b*48 + ox + dxlo - 2)*(48*52*128);
#pragma unroll
        for (int k = 0; k < 13; ++k)
            stg[k] = ok[k] ? *(const ushort8*)(slab + goff[k]) : zv;
#pragma unroll
        for (int k = 0; k < 13; ++k)
            *(ushort8*)(As + k*1024 + tid*8) = stg[k];
    }
    __syncthreads();

#pragma unroll 1
    for (int cc = 0; cc < 4; ++cc) {
#pragma unroll 1
      for (int dxi = 0; dxi < ndx; ++dxi) {
        const int dx = dxlo + dxi;

        // T14 issue-early: global loads for NEXT step into registers — the
        // 5-phase compute below (~6-8k cyc) hides their L2/HBM latency
        const int more = (dxi + 1 < ndx);
        const int cc2 = more ? cc : cc + 1;
        const int dx2 = more ? dx + 1 : dxlo;
        const bool do_stage = (cc2 < 4);
        if (do_stage) {
            const unsigned short* __restrict__ slab2 =
                xt + (size_t)(b*48 + ox + dx2 - 2)*(48*52*128) + cc2*32;
#pragma unroll
            for (int k = 0; k < 13; ++k)
                stg[k] = ok[k] ? *(const ushort8*)(slab2 + goff[k]) : zv;
        }

        // compute from As: dz-outer with B reg-cache; A rows r = oh + dy
        const unsigned short* __restrict__ wdxb =
            wp + (size_t)cc*128000 + (size_t)dx*25600 + l15*32 + l4*8;
        const char* __restrict__ asb = (const char*)As;
#pragma unroll
        for (int dz = 0; dz < 5; ++dz) {
            short8 bb[5][2];                 // B reg-cache for this dz
#pragma unroll
            for (int dy = 0; dy < 5; ++dy) {
                bb[dy][0] = *(const short8*)(wdxb + dy*5120 + dz*1024);
                bb[dy][1] = *(const short8*)(wdxb + dy*5120 + dz*1024 + 512);
            }
            __builtin_amdgcn_s_setprio(1);
#pragma unroll
            for (int r = 0; r < 6; ++r) {    // tile row = wave*2 + r
                const char* __restrict__ ab = asb + (wave*2 + r)*3328;
                short8 a[3];
#pragma unroll
                for (int zb = 0; zb < 3; ++zb) {
                    const int zp = l15 + dz + zb*16;
                    const int off = zp*64 + ((l4 ^ ((zp >> 1) & 3)) << 4);
                    a[zb] = *(const short8*)(ab + off);
                }
                if (r <= 4) {                // oh=0, dy=r
#pragma unroll
                    for (int zb = 0; zb < 3; ++zb) {
                        acc[0][zb][0] = MFMA16(a[zb], bb[r][0], acc[0][zb][0]);
                        acc[0][zb][1] = MFMA16(a[zb], bb[r][1], acc[0][zb][1]);
                    }
                }
                if (r >= 1) {                // oh=1, dy=r-1
#pragma unroll
                    for (int zb = 0; zb < 3; ++zb) {
                        acc[1][zb][0] = MFMA16(a[zb], bb[r-1][0], acc[1][zb][0]);
                        acc[1][zb][1] = MFMA16(a[zb], bb[r-1][1], acc[1][zb][1]);
                    }
                }
            }
            __builtin_amdgcn_s_setprio(0);
        }

        // write-late: all waves done reading As -> publish next tile
        __syncthreads();
        if (do_stage) {
#pragma unroll
            for (int k = 0; k < 13; ++k)
                *(ushort8*)(As + k*1024 + tid*8) = stg[k];
        }
        __syncthreads();
      }
    }

    float* gl = (float*)As;                   // 192*GLP f32 = 19,200 B < 26,624

    // C/D: col = lane&15 (co in tile), row = (lane>>4)*4 + r (z in 16-tile)
#pragma unroll
    for (int nt = 0; nt < 2; ++nt) {
        const int co = nt*16 + l15;
        if (co < NCO) {
#pragma unroll
            for (int oh = 0; oh < 2; ++oh)
#pragma unroll
              for (int zb = 0; zb < 3; ++zb)
#pragma unroll
                for (int r = 0; r < 4; ++r) {
                    const int z0 = zb*16 + l4*4 + r;
                    gl[((wave*2 + oh)*48 + z0)*GLP + co] =
                        1.f / (1.f + __expf(-acc[oh][zb][nt][r]));
                }
        }
    }
    __syncthreads();

    // epilogue: 384 items = (point 192) x (channel-half 2), fp32 x re-read
    for (int i = tid; i < 384; i += 128) {
        const int pnt = i % 192;
        const int half = i / 192;
        const int z = pnt % 48, oyl = pnt / 48;
        const int oy2 = oyq*4 + oyl;
        const size_t sp = ((size_t)ox*48 + oy2)*48 + z;
        const float* __restrict__ xsp = x   + (size_t)b*CIN*SSS + sp;
        float*       __restrict__ osp = out + (size_t)b*CIN*SSS + sp;
        const float* __restrict__ gp = gl + pnt*GLP;
        for (int c = half*60; c < half*60 + 60; ++c) {
            float v = xsp[(size_t)c*SSS];
            float o;
            if (c < 32)       o = v > 0.f ? v : 0.f;
            else if (c < 80)  o = v * gp[(c - 32) / 3];
            else              o = v * gp[16 + (c - 80) / 5];
            osp[(size_t)c*SSS] = o;
        }
    }
}

// ---------------- fallback paths (verified rounds 1-2) ----------------

__global__ __launch_bounds__(256)
void repack_w_f32(const float* __restrict__ w, float* __restrict__ wpf)
{
    int idx = blockIdx.x * 256 + threadIdx.x;
    if (idx >= WTOT_F32) return;
    int co = idx % NCO;
    int t  = idx / NCO;
    wpf[idx] = w[co * (CIN * NTAP) + t];
}

__global__ __launch_bounds__(128)
void gated_act_f32(const float* __restrict__ x,
                   const float* __restrict__ wpf,
                   float* __restrict__ out)
{
    const int gid = blockIdx.x * 128 + threadIdx.x;
    const int oz = gid % SDIM;
    int r = gid / SDIM;
    const int oy = r % SDIM; r /= SDIM;
    const int ox = r % SDIM;
    const int b  = r / SDIM;

    const float* __restrict__ xb = x + (size_t)b * CIN * SSS;
    float acc[NCO];
#pragma unroll
    for (int i = 0; i < NCO; ++i) acc[i] = 0.f;

    int izc[5]; bool okz[5];
#pragma unroll
    for (int dz = 0; dz < 5; ++dz) {
        int iz = oz + dz - 2;
        okz[dz] = (unsigned)iz < (unsigned)SDIM;
        izc[dz] = okz[dz] ? iz : 0;
    }
    for (int ci = 0; ci < CIN; ++ci) {
        const float* __restrict__ xc = xb + (size_t)ci * SSS;
        const float* __restrict__ wc = wpf + ci * (NTAP * NCO);
#pragma unroll 1
        for (int dx = 0; dx < 5; ++dx) {
            const int ix = ox + dx - 2;
            const bool okx = (unsigned)ix < (unsigned)SDIM;
            const int ixc = okx ? ix : 0;
#pragma unroll 1
            for (int dy = 0; dy < 5; ++dy) {
                const int iy = oy + dy - 2;
                const bool oky = (unsigned)iy < (unsigned)SDIM;
                const int iyc = oky ? iy : 0;
                const bool okxy = okx && oky;
                const float* __restrict__ xrow = xc + ixc * SS + iyc * SDIM;
                float xv[5];
#pragma unroll
                for (int dz = 0; dz < 5; ++dz) {
                    float v = xrow[izc[dz]];
                    xv[dz] = (okxy && okz[dz]) ? v : 0.f;
                }
                const float* __restrict__ wr = wc + (dx * 25 + dy * 5) * NCO;
#pragma unroll
                for (int dz = 0; dz < 5; ++dz) {
                    const float v = xv[dz];
#pragma unroll
                    for (int co = 0; co < NCO; ++co)
                        acc[co] = fmaf(v, wr[dz * NCO + co], acc[co]);
                }
            }
        }
    }
    float g[NCO];
#pragma unroll
    for (int co = 0; co < NCO; ++co)
        g[co] = 1.f / (1.f + __expf(-acc[co]));

    const size_t sbase = (size_t)b * CIN * SSS + ox * SS + oy * SDIM + oz;
    float* __restrict__ ob = out + sbase;
    const float* __restrict__ xs = x + sbase;
#pragma unroll
    for (int c = 0; c < 32; ++c) {
        float v = xs[(size_t)c * SSS];
        ob[(size_t)c * SSS] = v > 0.f ? v : 0.f;
    }
#pragma unroll
    for (int m = 0; m < 16; ++m) {
        const float gv = g[m];
#pragma unroll
        for (int k = 0; k < 3; ++k) {
            const int c = 32 + m * 3 + k;
            ob[(size_t)c * SSS] = xs[(size_t)c * SSS] * gv;
        }
    }
#pragma unroll
    for (int m = 0; m < 8; ++m) {
        const float gv = g[16 + m];
#pragma unroll
        for (int k = 0; k < 5; ++k) {
            const int c = 80 + m * 5 + k;
            ob[(size_t)c * SSS] = xs[(size_t)c * SSS] * gv;
        }
    }
}

extern "C" void kernel_launch(void* const* d_in, const int* in_sizes, int n_in,
                              void* d_out, int out_size, void* d_ws, size_t ws_size,
                              hipStream_t stream)
{
    const float* x = (const float*)d_in[0];
    const float* w = (const float*)d_in[1];
    float* out = (float*)d_out;

    if (ws_size >= WP_BYTES + XT_BYTES) {
        unsigned short* wp  = (unsigned short*)d_ws;
        unsigned short* xtb = (unsigned short*)((char*)d_ws + WP_BYTES);
        hipLaunchKernelGGL(repack_w_bf16, dim3((WP_USHORTS + 255) / 256), dim3(256),
                           0, stream, w, wp);
        hipLaunchKernelGGL(transpose_x, dim3(2*48*48), dim3(256), 0, stream, x, xtb);
        hipLaunchKernelGGL(conv_mfma, dim3(2*48*12), dim3(128), 0, stream,
                           xtb, wp, x, out);
    } else if (ws_size >= (size_t)WTOT_F32 * 4) {
        float* wpf = (float*)d_ws;
        hipLaunchKernelGGL(repack_w_f32, dim3((WTOT_F32 + 255) / 256), dim3(256),
                           0, stream, w, wpf);
        hipLaunchKernelGGL(gated_act_f32, dim3(2*SSS/128), dim3(128), 0, stream,
                           x, wpf, out);
    }
}

// Round 18
// 362.734 us; speedup vs baseline: 1.0822x; 1.0023x over previous
//
#include <hip/hip_runtime.h>

typedef __attribute__((ext_vector_type(8))) short short8;
typedef __attribute__((ext_vector_type(8))) unsigned short ushort8;
typedef __attribute__((ext_vector_type(4))) float f32x4;

#define SDIM 48
#define SS   (48*48)
#define SSS  (48*48*48)
#define CIN  120
#define CIP  128
#define NCO  24
#define ZP   52
#define NTAP 125

#define WP_USHORTS (4*25*5*32*32)              // 512000
#define WP_BYTES   ((size_t)WP_USHORTS*2)
#define XT_USHORTS ((size_t)2*48*48*ZP*CIP)
#define XT_BYTES   (XT_USHORTS*2)
#define WTOT_F32   (NCO*CIN*NTAP)

// A-tile in LDS: 1664 chunks of 16B at byte L*16 (L = k*128 + tid).
// chunk(row, zp, slot_phys): content = global ci-slot  slot_phys ^ ((zp>>1)&3).
// Read (row, zp, slot=l4) -> byte row*3328 + zp*64 + ((l4^((zp>>1)&3))<<4).
// 2-way bank aliasing = free (verified r9/r11: ~2.2e5 conflicts).
#define A_CHUNKS 1664
#define ABUF_USH 13312              // 26,624 B single buffer
#define GLP      25                 // gl pitch: odd -> bijective mod 32 banks

__device__ __forceinline__ unsigned short f2bf(float f){
    unsigned u = __float_as_uint(f);
    u = (u + 0x7FFFu + ((u >> 16) & 1u)) >> 16;
    return (unsigned short)u;
}

// ---------------- MFMA path ----------------

// x[b][ci][X][Y][Z] f32 -> xt[b][ix][iy][zp][ci] bf16 (zp=z+2 halo, ci pad 128)
__global__ __launch_bounds__(256)
void transpose_x(const float* __restrict__ x, unsigned short* __restrict__ xt)
{
    __shared__ unsigned short sm[CIN*50];
    int bid = blockIdx.x;
    const int iy = bid % 48; bid /= 48;
    const int ix = bid % 48;
    const int b  = bid / 48;
    const int tid = threadIdx.x;

    const float* __restrict__ src = x + (size_t)b*CIN*SSS + ((size_t)ix*48 + iy)*48;
    for (int idx = tid; idx < CIN*48; idx += 256) {
        int ci = idx / 48, z = idx - ci*48;
        sm[ci*50 + z] = f2bf(src[(size_t)ci*SSS + z]);
    }
    __syncthreads();
    unsigned short* __restrict__ dst = xt + (((size_t)(b*48 + ix)*48) + iy)*ZP*CIP;
    for (int odx = tid; odx < ZP*CIP; odx += 256) {
        int zp = odx >> 7, ci = odx & 127;
        int z = zp - 2;
        unsigned short v = 0;
        if (ci < CIN && (unsigned)z < 48u) v = sm[ci*50 + z];
        dst[odx] = v;
    }
}

// w[co][ci][dx][dy][dz] f32 -> wp[cc][t][dz][co 32][cik 32] bf16 (zero-padded)
__global__ __launch_bounds__(256)
void repack_w_bf16(const float* __restrict__ w, unsigned short* __restrict__ wp)
{
    int idx = blockIdx.x*256 + threadIdx.x;
    if (idx >= WP_USHORTS) return;
    int cik = idx & 31;
    int co  = (idx >> 5) & 31;
    int dz  = (idx >> 10) % 5;
    int t   = (idx / 5120) % 25;
    int cc  = idx / 128000;
    int ci  = cc*32 + cik;
    float v = 0.f;
    if (co < NCO && ci < CIN)
        v = w[(size_t)(co*CIN + ci)*NTAP + t*5 + dz];
    wp[idx] = f2bf(v);
}

#define MFMA16(a,b,c) __builtin_amdgcn_mfma_f32_16x16x32_bf16(a,b,c,0,0,0)

__global__ __launch_bounds__(128, 2)
void conv_mfma(const unsigned short* __restrict__ xt,
               const unsigned short* __restrict__ wp,
               const float* __restrict__ x,
               float* __restrict__ out)
{
    __shared__ __align__(16) unsigned short As[ABUF_USH];   // 26,624 B

    // bijective XCD swizzle: 1152 blocks = 8 XCDs x 144 contiguous logical ids
    int bid = (blockIdx.x & 7) * 144 + (blockIdx.x >> 3);
    const int oyq = bid % 12; bid /= 12;
    const int ox = bid % 48;
    const int b  = bid / 48;

    const int tid = threadIdx.x;            // 0..127, 2 waves
    const int lane = tid & 63;
    const int wave = tid >> 6;
    const int l15 = lane & 15, l4 = lane >> 4;
    const int iy0 = oyq*4 - 2;

    // valid dx range (block-uniform, contiguous): ix = ox+dx-2 in [0,48)
    const int dxlo = (ox < 2) ? (2 - ox) : 0;
    const int dxhi = (ox > 45) ? (49 - ox) : 4;
    const int ndx  = dxhi - dxlo + 1;

    // staging descriptors: 1664 chunks = 13 insts x 128 threads; thread tid
    // handles chunk L = k*128 + tid -> LDS byte L*16 (= ushort k*1024 + tid*8)
    int goff[13];
    bool ok[13];
#pragma unroll
    for (int k = 0; k < 13; ++k) {
        int L = k*128 + tid;
        int row = L / 208, rem = L - row*208;
        int zp = rem >> 2, sf = rem & 3;
        int sg = sf ^ ((zp >> 1) & 3);
        int iy = iy0 + row;
        ok[k]   = (unsigned)iy < 48u;
        goff[k] = (iy*52 + zp)*128 + sg*8;
    }
    const ushort8 zv = {0,0,0,0,0,0,0,0};

    // wave owns 2 oy lines (M=96): acc[oh][z-block][n-tile]
    f32x4 acc[2][3][2];
#pragma unroll
    for (int oh = 0; oh < 2; ++oh)
#pragma unroll
      for (int zb = 0; zb < 3; ++zb)
#pragma unroll
        for (int nt = 0; nt < 2; ++nt) acc[oh][zb][nt] = (f32x4){0,0,0,0};

    ushort8 stg[13];

    // prologue: load + write first tile (cc=0, dx=dxlo)
    {
        const unsigned short* __restrict__ slab =
            xt + (size_t)(b*48 + ox + dxlo - 2)*(48*52*128);
#pragma unroll
        for (int k = 0; k < 13; ++k)
            stg[k] = ok[k] ? *(const ushort8*)(slab + goff[k]) : zv;
#pragma unroll
        for (int k = 0; k < 13; ++k)
            *(ushort8*)(As + k*1024 + tid*8) = stg[k];
    }
    __syncthreads();

#pragma unroll 1
    for (int cc = 0; cc < 4; ++cc) {
#pragma unroll 1
      for (int dxi = 0; dxi < ndx; ++dxi) {
        const int dx = dxlo + dxi;

        const int more = (dxi + 1 < ndx);
        const int cc2 = more ? cc : cc + 1;
        const int dx2 = more ? dx + 1 : dxlo;
        const bool do_stage = (cc2 < 4);
        const unsigned short* __restrict__ slab2 =
            xt + (size_t)(b*48 + ox + dx2 - 2)*(48*52*128) + cc2*32;

        // compute from As: dz-outer with B reg-cache; A rows r = oh + dy.
        // KEY (vmcnt queue order): stg prefetch is issued AFTER dz=0's bb
        // loads, so the wait before dz=0's MFMAs excludes stg; the first
        // forced stg-drain is dz=1's bb use, ~1.4k cyc later (stg landed).
        const unsigned short* __restrict__ wdxb =
            wp + (size_t)cc*128000 + (size_t)dx*25600 + l15*32 + l4*8;
        const char* __restrict__ asb = (const char*)As;
#pragma unroll
        for (int dz = 0; dz < 5; ++dz) {
            short8 bb[5][2];                 // B reg-cache for this dz
#pragma unroll
            for (int dy = 0; dy < 5; ++dy) {
                bb[dy][0] = *(const short8*)(wdxb + dy*5120 + dz*1024);
                bb[dy][1] = *(const short8*)(wdxb + dy*5120 + dz*1024 + 512);
            }
            if (dz == 0) {
                // pin queue order: bb0 loads BEFORE stg, stg BEFORE bb1..4
                __builtin_amdgcn_sched_barrier(0);
                if (do_stage) {
#pragma unroll
                    for (int k = 0; k < 13; ++k)
                        stg[k] = ok[k] ? *(const ushort8*)(slab2 + goff[k]) : zv;
                }
                __builtin_amdgcn_sched_barrier(0);
            }
            __builtin_amdgcn_s_setprio(1);
#pragma unroll
            for (int r = 0; r < 6; ++r) {    // tile row = wave*2 + r
                const char* __restrict__ ab = asb + (wave*2 + r)*3328;
                short8 a[3];
#pragma unroll
                for (int zb = 0; zb < 3; ++zb) {
                    const int zp = l15 + dz + zb*16;
                    const int off = zp*64 + ((l4 ^ ((zp >> 1) & 3)) << 4);
                    a[zb] = *(const short8*)(ab + off);
                }
                if (r <= 4) {                // oh=0, dy=r
#pragma unroll
                    for (int zb = 0; zb < 3; ++zb) {
                        acc[0][zb][0] = MFMA16(a[zb], bb[r][0], acc[0][zb][0]);
                        acc[0][zb][1] = MFMA16(a[zb], bb[r][1], acc[0][zb][1]);
                    }
                }
                if (r >= 1) {                // oh=1, dy=r-1
#pragma unroll
                    for (int zb = 0; zb < 3; ++zb) {
                        acc[1][zb][0] = MFMA16(a[zb], bb[r-1][0], acc[1][zb][0]);
                        acc[1][zb][1] = MFMA16(a[zb], bb[r-1][1], acc[1][zb][1]);
                    }
                }
            }
            __builtin_amdgcn_s_setprio(0);
        }

        // write-late: all waves done reading As -> publish next tile
        __syncthreads();
        if (do_stage) {
#pragma unroll
            for (int k = 0; k < 13; ++k)
                *(ushort8*)(As + k*1024 + tid*8) = stg[k];
        }
        __syncthreads();
      }
    }

    float* gl = (float*)As;                   // 192*GLP f32 = 19,200 B < 26,624

    // C/D: col = lane&15 (co in tile), row = (lane>>4)*4 + r (z in 16-tile)
#pragma unroll
    for (int nt = 0; nt < 2; ++nt) {
        const int co = nt*16 + l15;
        if (co < NCO) {
#pragma unroll
            for (int oh = 0; oh < 2; ++oh)
#pragma unroll
              for (int zb = 0; zb < 3; ++zb)
#pragma unroll
                for (int r = 0; r < 4; ++r) {
                    const int z0 = zb*16 + l4*4 + r;
                    gl[((wave*2 + oh)*48 + z0)*GLP + co] =
                        1.f / (1.f + __expf(-acc[oh][zb][nt][r]));
                }
        }
    }
    __syncthreads();

    // epilogue: 384 items = (point 192) x (channel-half 2), fp32 x re-read
    for (int i = tid; i < 384; i += 128) {
        const int pnt = i % 192;
        const int half = i / 192;
        const int z = pnt % 48, oyl = pnt / 48;
        const int oy2 = oyq*4 + oyl;
        const size_t sp = ((size_t)ox*48 + oy2)*48 + z;
        const float* __restrict__ xsp = x   + (size_t)b*CIN*SSS + sp;
        float*       __restrict__ osp = out + (size_t)b*CIN*SSS + sp;
        const float* __restrict__ gp = gl + pnt*GLP;
        for (int c = half*60; c < half*60 + 60; ++c) {
            float v = xsp[(size_t)c*SSS];
            float o;
            if (c < 32)       o = v > 0.f ? v : 0.f;
            else if (c < 80)  o = v * gp[(c - 32) / 3];
            else              o = v * gp[16 + (c - 80) / 5];
            osp[(size_t)c*SSS] = o;
        }
    }
}

// ---------------- fallback paths (verified rounds 1-2) ----------------

__global__ __launch_bounds__(256)
void repack_w_f32(const float* __restrict__ w, float* __restrict__ wpf)
{
    int idx = blockIdx.x * 256 + threadIdx.x;
    if (idx >= WTOT_F32) return;
    int co = idx % NCO;
    int t  = idx / NCO;
    wpf[idx] = w[co * (CIN * NTAP) + t];
}

__global__ __launch_bounds__(128)
void gated_act_f32(const float* __restrict__ x,
                   const float* __restrict__ wpf,
                   float* __restrict__ out)
{
    const int gid = blockIdx.x * 128 + threadIdx.x;
    const int oz = gid % SDIM;
    int r = gid / SDIM;
    const int oy = r % SDIM; r /= SDIM;
    const int ox = r % SDIM;
    const int b  = r / SDIM;

    const float* __restrict__ xb = x + (size_t)b * CIN * SSS;
    float acc[NCO];
#pragma unroll
    for (int i = 0; i < NCO; ++i) acc[i] = 0.f;

    int izc[5]; bool okz[5];
#pragma unroll
    for (int dz = 0; dz < 5; ++dz) {
        int iz = oz + dz - 2;
        okz[dz] = (unsigned)iz < (unsigned)SDIM;
        izc[dz] = okz[dz] ? iz : 0;
    }
    for (int ci = 0; ci < CIN; ++ci) {
        const float* __restrict__ xc = xb + (size_t)ci * SSS;
        const float* __restrict__ wc = wpf + ci * (NTAP * NCO);
#pragma unroll 1
        for (int dx = 0; dx < 5; ++dx) {
            const int ix = ox + dx - 2;
            const bool okx = (unsigned)ix < (unsigned)SDIM;
            const int ixc = okx ? ix : 0;
#pragma unroll 1
            for (int dy = 0; dy < 5; ++dy) {
                const int iy = oy + dy - 2;
                const bool oky = (unsigned)iy < (unsigned)SDIM;
                const int iyc = oky ? iy : 0;
                const bool okxy = okx && oky;
                const float* __restrict__ xrow = xc + ixc * SS + iyc * SDIM;
                float xv[5];
#pragma unroll
                for (int dz = 0; dz < 5; ++dz) {
                    float v = xrow[izc[dz]];
                    xv[dz] = (okxy && okz[dz]) ? v : 0.f;
                }
                const float* __restrict__ wr = wc + (dx * 25 + dy * 5) * NCO;
#pragma unroll
                for (int dz = 0; dz < 5; ++dz) {
                    const float v = xv[dz];
#pragma unroll
                    for (int co = 0; co < NCO; ++co)
                        acc[co] = fmaf(v, wr[dz * NCO + co], acc[co]);
                }
            }
        }
    }
    float g[NCO];
#pragma unroll
    for (int co = 0; co < NCO; ++co)
        g[co] = 1.f / (1.f + __expf(-acc[co]));

    const size_t sbase = (size_t)b * CIN * SSS + ox * SS + oy * SDIM + oz;
    float* __restrict__ ob = out + sbase;
    const float* __restrict__ xs = x + sbase;
#pragma unroll
    for (int c = 0; c < 32; ++c) {
        float v = xs[(size_t)c * SSS];
        ob[(size_t)c * SSS] = v > 0.f ? v : 0.f;
    }
#pragma unroll
    for (int m = 0; m < 16; ++m) {
        const float gv = g[m];
#pragma unroll
        for (int k = 0; k < 3; ++k) {
            const int c = 32 + m * 3 + k;
            ob[(size_t)c * SSS] = xs[(size_t)c * SSS] * gv;
        }
    }
#pragma unroll
    for (int m = 0; m < 8; ++m) {
        const float gv = g[16 + m];
#pragma unroll
        for (int k = 0; k < 5; ++k) {
            const int c = 80 + m * 5 + k;
            ob[(size_t)c * SSS] = xs[(size_t)c * SSS] * gv;
        }
    }
}

extern "C" void kernel_launch(void* const* d_in, const int* in_sizes, int n_in,
                              void* d_out, int out_size, void* d_ws, size_t ws_size,
                              hipStream_t stream)
{
    const float* x = (const float*)d_in[0];
    const float* w = (const float*)d_in[1];
    float* out = (float*)d_out;

    if (ws_size >= WP_BYTES + XT_BYTES) {
        unsigned short* wp  = (unsigned short*)d_ws;
        unsigned short* xtb = (unsigned short*)((char*)d_ws + WP_BYTES);
        hipLaunchKernelGGL(repack_w_bf16, dim3((WP_USHORTS + 255) / 256), dim3(256),
                           0, stream, w, wp);
        hipLaunchKernelGGL(transpose_x, dim3(2*48*48), dim3(256), 0, stream, x, xtb);
        hipLaunchKernelGGL(conv_mfma, dim3(2*48*12), dim3(128), 0, stream,
                           xtb, wp, x, out);
    } else if (ws_size >= (size_t)WTOT_F32 * 4) {
        float* wpf = (float*)d_ws;
        hipLaunchKernelGGL(repack_w_f32, dim3((WTOT_F32 + 255) / 256), dim3(256),
                           0, stream, w, wpf);
        hipLaunchKernelGGL(gated_act_f32, dim3(2*SSS/128), dim3(128), 0, stream,
                           x, wpf, out);
    }
}

// Round 19
// 317.586 us; speedup vs baseline: 1.2360x; 1.1422x over previous
//
#include <hip/hip_runtime.h>

typedef __attribute__((ext_vector_type(8))) short short8;
typedef __attribute__((ext_vector_type(4))) float f32x4;

#define SDIM 48
#define SS   (48*48)
#define SSS  (48*48*48)
#define CIN  120
#define CIP  128
#define NCO  24
#define ZP   52
#define NTAP 125

#define WP_USHORTS (4*25*5*32*32)              // 512000
#define WP_BYTES   ((size_t)WP_USHORTS*2)
#define XT_USHORTS ((size_t)2*48*48*ZP*CIP)
#define XT_BYTES   (XT_USHORTS*2)
#define WTOT_F32   (NCO*CIN*NTAP)

// A-tile in LDS: 1664 chunks of 16B, linear in gload_lds order.
// chunk(row, zp, slot_phys): content = global ci-slot  slot_phys ^ ((zp>>1)&3).
// Read (row, zp, slot=l4) -> byte row*3328 + zp*64 + ((l4^((zp>>1)&3))<<4).
// Bank-group = (4(zp&1) + l4^((zp>>1)&3))&7: 2-way = free (verified r9: 2.2e5).
#define A_CHUNKS 1664
#define ABUF_USH 13312              // 26,624 B single buffer -> 6 blocks/CU
#define GLP      25                 // gl pitch: odd -> bijective mod 32 banks

__device__ __forceinline__ unsigned short f2bf(float f){
    unsigned u = __float_as_uint(f);
    u = (u + 0x7FFFu + ((u >> 16) & 1u)) >> 16;
    return (unsigned short)u;
}

__device__ __forceinline__ void gload_lds16(const unsigned short* g, unsigned short* l)
{
    __builtin_amdgcn_global_load_lds(
        (const __attribute__((address_space(1))) unsigned int*)g,
        (__attribute__((address_space(3))) unsigned int*)l,
        16, 0, 0);
}

// ---------------- MFMA path ----------------

// x[b][ci][X][Y][Z] f32 -> xt[b][ix][iy][zp][ci] bf16 (zp=z+2 halo, ci pad 128)
__global__ __launch_bounds__(256)
void transpose_x(const float* __restrict__ x, unsigned short* __restrict__ xt)
{
    __shared__ unsigned short sm[CIN*50];
    int bid = blockIdx.x;
    const int iy = bid % 48; bid /= 48;
    const int ix = bid % 48;
    const int b  = bid / 48;
    const int tid = threadIdx.x;

    const float* __restrict__ src = x + (size_t)b*CIN*SSS + ((size_t)ix*48 + iy)*48;
    for (int idx = tid; idx < CIN*48; idx += 256) {
        int ci = idx / 48, z = idx - ci*48;
        sm[ci*50 + z] = f2bf(src[(size_t)ci*SSS + z]);
    }
    __syncthreads();
    unsigned short* __restrict__ dst = xt + (((size_t)(b*48 + ix)*48) + iy)*ZP*CIP;
    for (int odx = tid; odx < ZP*CIP; odx += 256) {
        int zp = odx >> 7, ci = odx & 127;
        int z = zp - 2;
        unsigned short v = 0;
        if (ci < CIN && (unsigned)z < 48u) v = sm[ci*50 + z];
        dst[odx] = v;
    }
}

// w[co][ci][dx][dy][dz] f32 -> wp[cc][t][dz][co 32][cik 32] bf16 (zero-padded)
__global__ __launch_bounds__(256)
void repack_w_bf16(const float* __restrict__ w, unsigned short* __restrict__ wp)
{
    int idx = blockIdx.x*256 + threadIdx.x;
    if (idx >= WP_USHORTS) return;
    int cik = idx & 31;
    int co  = (idx >> 5) & 31;
    int dz  = (idx >> 10) % 5;
    int t   = (idx / 5120) % 25;
    int cc  = idx / 128000;
    int ci  = cc*32 + cik;
    float v = 0.f;
    if (co < NCO && ci < CIN)
        v = w[(size_t)(co*CIN + ci)*NTAP + t*5 + dz];
    wp[idx] = f2bf(v);
}

#define MFMA16(a,b,c) __builtin_amdgcn_mfma_f32_16x16x32_bf16(a,b,c,0,0,0)

__global__ __launch_bounds__(128, 3)
void conv_mfma(const unsigned short* __restrict__ xt,
               const unsigned short* __restrict__ wp,
               const float* __restrict__ x,
               float* __restrict__ out)
{
    __shared__ __align__(16) unsigned short As[ABUF_USH];   // 26,624 B

    // bijective XCD swizzle: 1152 blocks = 8 XCDs x 144 contiguous logical ids
    int bid = (blockIdx.x & 7) * 144 + (blockIdx.x >> 3);
    const int oyq = bid % 12; bid /= 12;
    const int ox = bid % 48;
    const int b  = bid / 48;

    const int tid = threadIdx.x;        // 0..127, 2 waves
    const int wave = tid >> 6, lane = tid & 63;
    const int l15 = lane & 15, l4 = lane >> 4;
    const int iy0 = oyq*4 - 2;

    // valid dx range (block-uniform, contiguous): ix = ox+dx-2 in [0,48)
    const int dxlo = (ox < 2) ? (2 - ox) : 0;
    const int dxhi = (ox > 45) ? (49 - ox) : 4;
    const int ndx  = dxhi - dxlo + 1;

    // staging descriptors: 1664 chunks = 13 insts x 128 threads
    int goff[13];
    bool ok[13];
#pragma unroll
    for (int k = 0; k < 13; ++k) {
        int L = k*128 + tid;
        int row = L / 208, rem = L - row*208;
        int zp = rem >> 2, sf = rem & 3;
        int sg = sf ^ ((zp >> 1) & 3);
        int iy = iy0 + row;
        ok[k]   = (unsigned)iy < 48u;
        goff[k] = (iy*52 + zp)*128 + sg*8;
    }
    // zero source: xt's leading 512B (zp=0,1 halo of b=0,ix=0,iy=0) is all zeros
    const unsigned short* zsrc = xt + (lane & 31)*8;

    // wave owns 2 oy lines (M=96): acc[oh][z-block][n-tile]
    f32x4 acc[2][3][2];
#pragma unroll
    for (int oh = 0; oh < 2; ++oh)
#pragma unroll
      for (int zb = 0; zb < 3; ++zb)
#pragma unroll
        for (int nt = 0; nt < 2; ++nt) acc[oh][zb][nt] = (f32x4){0,0,0,0};

#pragma unroll 1
    for (int cc = 0; cc < 4; ++cc) {
#pragma unroll 1
      for (int dxi = 0; dxi < ndx; ++dxi) {
        const int dx = dxlo + dxi;
        const int ix = ox + dx - 2;
        const unsigned short* __restrict__ slab =
            xt + (size_t)(b*48 + ix)*(48*52*128) + cc*32;

        __syncthreads();   // all waves done reading As for previous step
#pragma unroll
        for (int k = 0; k < 13; ++k) {
            const unsigned short* src = ok[k] ? (slab + goff[k]) : zsrc;
            gload_lds16(src, As + k*1024 + wave*512);
        }
        asm volatile("s_waitcnt vmcnt(0)" ::: "memory");
        __builtin_amdgcn_sched_barrier(0);
        __syncthreads();   // DMA from both waves visible

        // compute: dz-outer, iy-row inner; each A ds_read feeds 4 MFMAs
        // (rows wave*2+oh+dy collide: (dy,oh=0) and (dy-1,oh=1) share the row)
        const unsigned short* __restrict__ wdxb =
            wp + (size_t)cc*128000 + (size_t)dx*25600 + l15*32 + l4*8;
        const char* __restrict__ asb = (const char*)As;
#pragma unroll
        for (int dz = 0; dz < 5; ++dz) {
            short8 bb[5][2];                 // B reg-cache for this dz
#pragma unroll
            for (int dy = 0; dy < 5; ++dy) {
                bb[dy][0] = *(const short8*)(wdxb + dy*5120 + dz*1024);
                bb[dy][1] = *(const short8*)(wdxb + dy*5120 + dz*1024 + 512);
            }
#pragma unroll
            for (int r = 0; r < 6; ++r) {    // tile iy row = wave*2 + r
                const char* __restrict__ ab = asb + (wave*2 + r)*3328;
                short8 a[3];
#pragma unroll
                for (int zb = 0; zb < 3; ++zb) {
                    const int zp = l15 + dz + zb*16;
                    const int off = zp*64 + ((l4 ^ ((zp >> 1) & 3)) << 4);
                    a[zb] = *(const short8*)(ab + off);
                }
                if (r <= 4) {                // oh=0, dy=r
#pragma unroll
                    for (int zb = 0; zb < 3; ++zb) {
                        acc[0][zb][0] = MFMA16(a[zb], bb[r][0], acc[0][zb][0]);
                        acc[0][zb][1] = MFMA16(a[zb], bb[r][1], acc[0][zb][1]);
                    }
                }
                if (r >= 1) {                // oh=1, dy=r-1
#pragma unroll
                    for (int zb = 0; zb < 3; ++zb) {
                        acc[1][zb][0] = MFMA16(a[zb], bb[r-1][0], acc[1][zb][0]);
                        acc[1][zb][1] = MFMA16(a[zb], bb[r-1][1], acc[1][zb][1]);
                    }
                }
            }
        }
      }
    }

    __syncthreads();                          // As -> gl reuse
    float* gl = (float*)As;                   // 192*GLP f32 = 19,200 B < 26,624

    // C/D: col = lane&15 (co in tile), row = (lane>>4)*4 + r (z in 16-tile)
#pragma unroll
    for (int nt = 0; nt < 2; ++nt) {
        const int co = nt*16 + l15;
        if (co < NCO) {
#pragma unroll
            for (int oh = 0; oh < 2; ++oh)
#pragma unroll
              for (int zb = 0; zb < 3; ++zb)
#pragma unroll
                for (int r = 0; r < 4; ++r) {
                    const int z0 = zb*16 + l4*4 + r;
                    gl[((wave*2 + oh)*48 + z0)*GLP + co] =
                        1.f / (1.f + __expf(-acc[oh][zb][nt][r]));
                }
        }
    }
    __syncthreads();

    // epilogue: 384 items = (point 192) x (channel-half 2), fp32 x re-read
    for (int i = tid; i < 384; i += 128) {
        const int pnt = i % 192;
        const int half = i / 192;
        const int z = pnt % 48, oyl = pnt / 48;
        const int oy2 = oyq*4 + oyl;
        const size_t sp = ((size_t)ox*48 + oy2)*48 + z;
        const float* __restrict__ xsp = x   + (size_t)b*CIN*SSS + sp;
        float*       __restrict__ osp = out + (size_t)b*CIN*SSS + sp;
        const float* __restrict__ gp = gl + pnt*GLP;
        for (int c = half*60; c < half*60 + 60; ++c) {
            float v = xsp[(size_t)c*SSS];
            float o;
            if (c < 32)       o = v > 0.f ? v : 0.f;
            else if (c < 80)  o = v * gp[(c - 32) / 3];
            else              o = v * gp[16 + (c - 80) / 5];
            osp[(size_t)c*SSS] = o;
        }
    }
}

// ---------------- fallback paths (verified rounds 1-2) ----------------

__global__ __launch_bounds__(256)
void repack_w_f32(const float* __restrict__ w, float* __restrict__ wpf)
{
    int idx = blockIdx.x * 256 + threadIdx.x;
    if (idx >= WTOT_F32) return;
    int co = idx % NCO;
    int t  = idx / NCO;
    wpf[idx] = w[co * (CIN * NTAP) + t];
}

__global__ __launch_bounds__(128)
void gated_act_f32(const float* __restrict__ x,
                   const float* __restrict__ wpf,
                   float* __restrict__ out)
{
    const int gid = blockIdx.x * 128 + threadIdx.x;
    const int oz = gid % SDIM;
    int r = gid / SDIM;
    const int oy = r % SDIM; r /= SDIM;
    const int ox = r % SDIM;
    const int b  = r / SDIM;

    const float* __restrict__ xb = x + (size_t)b * CIN * SSS;
    float acc[NCO];
#pragma unroll
    for (int i = 0; i < NCO; ++i) acc[i] = 0.f;

    int izc[5]; bool okz[5];
#pragma unroll
    for (int dz = 0; dz < 5; ++dz) {
        int iz = oz + dz - 2;
        okz[dz] = (unsigned)iz < (unsigned)SDIM;
        izc[dz] = okz[dz] ? iz : 0;
    }
    for (int ci = 0; ci < CIN; ++ci) {
        const float* __restrict__ xc = xb + (size_t)ci * SSS;
        const float* __restrict__ wc = wpf + ci * (NTAP * NCO);
#pragma unroll 1
        for (int dx = 0; dx < 5; ++dx) {
            const int ix = ox + dx - 2;
            const bool okx = (unsigned)ix < (unsigned)SDIM;
            const int ixc = okx ? ix : 0;
#pragma unroll 1
            for (int dy = 0; dy < 5; ++dy) {
                const int iy = oy + dy - 2;
                const bool oky = (unsigned)iy < (unsigned)SDIM;
                const int iyc = oky ? iy : 0;
                const bool okxy = okx && oky;
                const float* __restrict__ xrow = xc + ixc * SS + iyc * SDIM;
                float xv[5];
#pragma unroll
                for (int dz = 0; dz < 5; ++dz) {
                    float v = xrow[izc[dz]];
                    xv[dz] = (okxy && okz[dz]) ? v : 0.f;
                }
                const float* __restrict__ wr = wc + (dx * 25 + dy * 5) * NCO;
#pragma unroll
                for (int dz = 0; dz < 5; ++dz) {
                    const float v = xv[dz];
#pragma unroll
                    for (int co = 0; co < NCO; ++co)
                        acc[co] = fmaf(v, wr[dz * NCO + co], acc[co]);
                }
            }
        }
    }
    float g[NCO];
#pragma unroll
    for (int co = 0; co < NCO; ++co)
        g[co] = 1.f / (1.f + __expf(-acc[co]));

    const size_t sbase = (size_t)b * CIN * SSS + ox * SS + oy * SDIM + oz;
    float* __restrict__ ob = out + sbase;
    const float* __restrict__ xs = x + sbase;
#pragma unroll
    for (int c = 0; c < 32; ++c) {
        float v = xs[(size_t)c * SSS];
        ob[(size_t)c * SSS] = v > 0.f ? v : 0.f;
    }
#pragma unroll
    for (int m = 0; m < 16; ++m) {
        const float gv = g[m];
#pragma unroll
        for (int k = 0; k < 3; ++k) {
            const int c = 32 + m * 3 + k;
            ob[(size_t)c * SSS] = xs[(size_t)c * SSS] * gv;
        }
    }
#pragma unroll
    for (int m = 0; m < 8; ++m) {
        const float gv = g[16 + m];
#pragma unroll
        for (int k = 0; k < 5; ++k) {
            const int c = 80 + m * 5 + k;
            ob[(size_t)c * SSS] = xs[(size_t)c * SSS] * gv;
        }
    }
}

extern "C" void kernel_launch(void* const* d_in, const int* in_sizes, int n_in,
                              void* d_out, int out_size, void* d_ws, size_t ws_size,
                              hipStream_t stream)
{
    const float* x = (const float*)d_in[0];
    const float* w = (const float*)d_in[1];
    float* out = (float*)d_out;

    if (ws_size >= WP_BYTES + XT_BYTES) {
        unsigned short* wp  = (unsigned short*)d_ws;
        unsigned short* xtb = (unsigned short*)((char*)d_ws + WP_BYTES);
        hipLaunchKernelGGL(repack_w_bf16, dim3((WP_USHORTS + 255) / 256), dim3(256),
                           0, stream, w, wp);
        hipLaunchKernelGGL(transpose_x, dim3(2*48*48), dim3(256), 0, stream, x, xtb);
        hipLaunchKernelGGL(conv_mfma, dim3(2*48*12), dim3(128), 0, stream,
                           xtb, wp, x, out);
    } else if (ws_size >= (size_t)WTOT_F32 * 4) {
        float* wpf = (float*)d_ws;
        hipLaunchKernelGGL(repack_w_f32, dim3((WTOT_F32 + 255) / 256), dim3(256),
                           0, stream, w, wpf);
        hipLaunchKernelGGL(gated_act_f32, dim3(2*SSS/128), dim3(128), 0, stream,
                           x, wpf, out);
    }
}